// Round 2
// baseline (265.433 us; speedup 1.0000x reference)
//
#include <hip/hip_runtime.h>
#include <stdint.h>

// NVFP4Linear: M=128 (8x16), K=I=8192, N=O=8192
// d_in[0] hidden: f32 [128][8192]  (reference fp16 promoted to f32 by harness)
// d_in[1] weight: int32[8192][4096], one packed byte per int (low nibble = even k)
// d_in[2] weight_scale: f32 [8192][512] (per 16-k group)
// d_in[3] weight_scale_2: f32[1] ; d_in[4] input_scale: f32[1]
// d_out: f32 [128][8192]

typedef _Float16 half8 __attribute__((ext_vector_type(8)));
typedef float float4v __attribute__((ext_vector_type(4)));

__device__ __forceinline__ uint32_t perm_b32(uint32_t hi, uint32_t lo, uint32_t sel) {
  return __builtin_amdgcn_perm(hi, lo, sel);
}

// RNE round-trip through fp8 e4m3fn (x >= 0, finite)
__device__ __forceinline__ float e4m3_roundtrip(float x) {
  if (x < 0.015625f) {               // subnormal region: grid step 2^-9
    return __builtin_rintf(x * 512.0f) * 0.001953125f;
  }
  uint32_t u = __float_as_uint(x);
  u += 0x7FFFFu + ((u >> 20) & 1u);  // RNE to 3 mantissa bits
  u &= 0xFFF00000u;
  float y = __uint_as_float(u);
  return fminf(y, 448.0f);
}

// ---------------- Kernel 1: activation QDQ -> swizzled f16 A fragments ----------------
// A_sw fragment (kb, mb) = 64 lanes x 16B; lane l holds A[mb*16 + (l&15)][kb*32 + (l>>4)*8 + j]
// 4 lanes cooperate per 16-element group (shfl_xor amax) -> 262144 threads, 4096 waves.
__global__ __launch_bounds__(256)
void aqdq_kernel(const float* __restrict__ hs,
                 const float* __restrict__ isc,
                 uint2* __restrict__ asw) {
  const int t = blockIdx.x * 256 + threadIdx.x;   // 262144 total
  const int m = t >> 11;                          // row 0..127
  const int u = t & 2047;
  const int g = u >> 2;                           // group within row 0..511
  const int hq = u & 3;                           // quarter of group

  const float* p = hs + m * 8192 + g * 16 + hq * 4;
  float4 x = *(const float4*)p;

  float amax = fmaxf(fmaxf(fabsf(x.x), fabsf(x.y)), fmaxf(fabsf(x.z), fabsf(x.w)));
  amax = fmaxf(amax, __shfl_xor(amax, 1));
  amax = fmaxf(amax, __shfl_xor(amax, 2));

  float is = isc[0];
  float s = e4m3_roundtrip(amax / (6.0f * is));
  if (!(s > 0.0f)) s = 1.0f;
  float total = s * is;

  float xv[4] = {x.x, x.y, x.z, x.w};
  union { _Float16 h[4]; uint2 v; } qq;
#pragma unroll
  for (int i = 0; i < 4; ++i) {
    float r = xv[i] / total;         // correctly-rounded f32 div, matches jnp
    float a = fabsf(r);
    // E2M1 nearest; ties -> lower magnitude (searchsorted side='left')
    float v = (a <= 0.25f) ? 0.0f
            : (a <= 0.75f) ? 0.5f
            : (a <= 1.25f) ? 1.0f
            : (a <= 1.75f) ? 1.5f
            : (a <= 2.5f)  ? 2.0f
            : (a <= 3.5f)  ? 3.0f
            : (a <= 5.0f)  ? 4.0f : 6.0f;
    qq.h[i] = (_Float16)(copysignf(v, r) * total);  // exact in f16
  }

  const int k = g * 16 + hq * 4;
  const int kb = k >> 5;
  const int quad = (k >> 3) & 3;
  const int lane16 = (m & 15) | (quad << 4);
  const int mb = m >> 4;
  asw[((kb * 8 + mb) * 64 + lane16) * 2 + (hq & 1)] = qq.v;
}

// ---------------- fp4 pair decode: 4 packed bytes (8 codes) -> 8 scaled f16 ----------------
__device__ __forceinline__ half8 decode_scale(int4 w, float sf) {
  uint32_t t0 = perm_b32((uint32_t)w.y, (uint32_t)w.x, 0x00000400u);
  uint32_t t1 = perm_b32((uint32_t)w.w, (uint32_t)w.z, 0x04000000u);
  uint32_t b  = perm_b32(t1, t0, 0x07060100u); // byte i = codes (k2i, k2i+1)
  uint32_t ev = b & 0x0F0F0F0Fu;               // even-k nibbles
  uint32_t od = (b >> 4) & 0x0F0F0F0Fu;        // odd-k nibbles
  uint32_t evm = ev & 0x07070707u;
  uint32_t odm = od & 0x07070707u;
  uint32_t evs = (ev & 0x08080808u) << 4;      // sign -> byte-high bit (f16 bit15)
  uint32_t ods = (od & 0x08080808u) << 4;
  // f16 high bytes of {0,.5,1,1.5,2,3,4,6} = {00,38,3C,3E,40,42,44,46}
  uint32_t evh = perm_b32(0x46444240u, 0x3E3C3800u, evm) | evs;
  uint32_t odh = perm_b32(0x46444240u, 0x3E3C3800u, odm) | ods;
  union { uint32_t u[4]; half8 h; } r;
  r.u[0] = perm_b32(odh, evh, 0x04000000u) & 0xFF00FF00u; // (k1,k0)
  r.u[1] = perm_b32(odh, evh, 0x05000100u) & 0xFF00FF00u; // (k3,k2)
  r.u[2] = perm_b32(odh, evh, 0x06000200u) & 0xFF00FF00u; // (k5,k4)
  r.u[3] = perm_b32(odh, evh, 0x07000300u) & 0xFF00FF00u; // (k7,k6)
  _Float16 hsf = (_Float16)sf;
  half8 sv = {hsf, hsf, hsf, hsf, hsf, hsf, hsf, hsf};
  return r.h * sv;                              // v_pk_mul_f16 x4
}

// ---------------- Kernel 2: fused dequant GEMM ----------------
// 512 blocks x 512 threads. Block b: n-cols [b*16, b*16+16). Wave wv = k-part (1024 k each).
// LDS cut to 67.6 KiB -> 2 blocks/CU (16 waves/CU); VGPR capped at 128 via launch_bounds.
// No barriers in the K loop; K-split reduced once through LDS at the end.
__global__ __launch_bounds__(512, 4)
void gemm_kernel(const uint4* __restrict__ asw,
                 const int* __restrict__ wq,
                 const float* __restrict__ wsc,
                 const float* __restrict__ ws2p,
                 float* __restrict__ out) {
  __shared__ float red[8][16][132];   // [kpart][n_local][m], stride 132 (==4 mod 32: 2-way banked reads)
  const int lane = threadIdx.x & 63;
  const int wv = threadIdx.x >> 6;    // k-part 0..7
  const int quad = lane >> 4;
  const int n0 = blockIdx.x * 16;
  const int rA = n0 + (lane & 15);
  const float ws2 = ws2p[0];
  const int4* wpA = (const int4*)(wq + rA * 4096);
  const float* wsA = wsc + rA * 512;
  const int kbase = wv * 1024;

  float4v acc[8];
#pragma unroll
  for (int mb = 0; mb < 8; ++mb) acc[mb] = (float4v){0.f, 0.f, 0.f, 0.f};

  const uint4* ap = asw + (kbase >> 5) * 512 + lane;

#pragma unroll 2
  for (int ks = 0; ks < 32; ++ks) {
    const int k0 = kbase + ks * 32;
    int4 wA = wpA[(k0 >> 3) + quad];
    float2 sv = *(const float2*)(wsA + (k0 >> 4));       // both group scales for this k32
    float sA = ((quad & 2) ? sv.y : sv.x) * ws2;
    uint4 af[8];
#pragma unroll
    for (int mb = 0; mb < 8; ++mb) af[mb] = ap[ks * 512 + mb * 64];
    half8 bA = decode_scale(wA, sA);
#pragma unroll
    for (int mb = 0; mb < 8; ++mb) {
      union { uint4 u; half8 h; } a;
      a.u = af[mb];
      acc[mb] = __builtin_amdgcn_mfma_f32_16x16x32_f16(a.h, bA, acc[mb], 0, 0, 0);
    }
  }

  // K-split reduction. C/D layout: n = lane&15, m = quad*4 + reg (verified m89/m91)
#pragma unroll
  for (int mb = 0; mb < 8; ++mb) {
    *(float4v*)&red[wv][lane & 15][mb * 16 + quad * 4] = acc[mb];
  }
  __syncthreads();

  const int t = threadIdx.x;
  const int m = t >> 2;          // 0..127
  const int j0 = (t & 3) * 4;    // 0,4,8,12
  float o[4];
#pragma unroll
  for (int j = 0; j < 4; ++j) {
    float s = 0.f;
#pragma unroll
    for (int p = 0; p < 8; ++p) s += red[p][j0 + j][m];
    o[j] = s;
  }
  *(float4*)&out[m * 8192 + n0 + j0] = *(float4*)&o[0];
}

extern "C" void kernel_launch(void* const* d_in, const int* in_sizes, int n_in,
                              void* d_out, int out_size, void* d_ws, size_t ws_size,
                              hipStream_t stream) {
  (void)in_sizes; (void)n_in; (void)out_size; (void)ws_size;
  const float* hs  = (const float*)d_in[0];   // f32 [128][8192]
  const int* wq    = (const int*)d_in[1];     // int32 [8192][4096]
  const float* wsc = (const float*)d_in[2];   // f32 [8192][512]
  const float* ws2 = (const float*)d_in[3];   // f32 [1]
  const float* isc = (const float*)d_in[4];   // f32 [1]
  float* out       = (float*)d_out;           // f32 [128][8192]
  uint2* asw2      = (uint2*)d_ws;            // 2 MiB swizzled f16 A fragments (8B store view)
  const uint4* asw4 = (const uint4*)d_ws;     // same buffer, 16B fragment view

  aqdq_kernel<<<1024, 256, 0, stream>>>(hs, isc, asw2);
  gemm_kernel<<<512, 512, 0, stream>>>(asw4, wq, wsc, ws2, out);
}

// Round 3
// 241.914 us; speedup vs baseline: 1.0972x; 1.0972x over previous
//
#include <hip/hip_runtime.h>
#include <stdint.h>

// NVFP4Linear: M=128 (8x16), K=I=8192, N=O=8192
// d_in[0] hidden: f32 [128][8192]  (reference fp16 promoted to f32 by harness)
// d_in[1] weight: int32[8192][4096], one packed byte per int (low nibble = even k)
// d_in[2] weight_scale: f32 [8192][512] (per 16-k group)
// d_in[3] weight_scale_2: f32[1] ; d_in[4] input_scale: f32[1]
// d_out: f32 [128][8192]

typedef _Float16 half8 __attribute__((ext_vector_type(8)));
typedef float float4v __attribute__((ext_vector_type(4)));

__device__ __forceinline__ uint32_t perm_b32(uint32_t hi, uint32_t lo, uint32_t sel) {
  return __builtin_amdgcn_perm(hi, lo, sel);
}

// RNE round-trip through fp8 e4m3fn (x >= 0, finite)
__device__ __forceinline__ float e4m3_roundtrip(float x) {
  if (x < 0.015625f) {               // subnormal region: grid step 2^-9
    return __builtin_rintf(x * 512.0f) * 0.001953125f;
  }
  uint32_t u = __float_as_uint(x);
  u += 0x7FFFFu + ((u >> 20) & 1u);  // RNE to 3 mantissa bits
  u &= 0xFFF00000u;
  float y = __uint_as_float(u);
  return fminf(y, 448.0f);
}

// ---------------- Kernel 1: activation QDQ -> swizzled f16 A fragments ----------------
// A_sw fragment (kb, mb) = 64 lanes x 16B; lane l holds A[mb*16 + (l&15)][kb*32 + (l>>4)*8 + j]
// 4 lanes cooperate per 16-element group (shfl_xor amax) -> 262144 threads, 4096 waves.
__global__ __launch_bounds__(256)
void aqdq_kernel(const float* __restrict__ hs,
                 const float* __restrict__ isc,
                 uint2* __restrict__ asw) {
  const int t = blockIdx.x * 256 + threadIdx.x;   // 262144 total
  const int m = t >> 11;                          // row 0..127
  const int u = t & 2047;
  const int g = u >> 2;                           // group within row 0..511
  const int hq = u & 3;                           // quarter of group

  const float* p = hs + m * 8192 + g * 16 + hq * 4;
  float4 x = *(const float4*)p;

  float amax = fmaxf(fmaxf(fabsf(x.x), fabsf(x.y)), fmaxf(fabsf(x.z), fabsf(x.w)));
  amax = fmaxf(amax, __shfl_xor(amax, 1));
  amax = fmaxf(amax, __shfl_xor(amax, 2));

  float is = isc[0];
  float s = e4m3_roundtrip(amax / (6.0f * is));
  if (!(s > 0.0f)) s = 1.0f;
  float total = s * is;

  float xv[4] = {x.x, x.y, x.z, x.w};
  union { _Float16 h[4]; uint2 v; } qq;
#pragma unroll
  for (int i = 0; i < 4; ++i) {
    float r = xv[i] / total;         // correctly-rounded f32 div, matches jnp
    float a = fabsf(r);
    // E2M1 nearest; ties -> lower magnitude (searchsorted side='left')
    float v = (a <= 0.25f) ? 0.0f
            : (a <= 0.75f) ? 0.5f
            : (a <= 1.25f) ? 1.0f
            : (a <= 1.75f) ? 1.5f
            : (a <= 2.5f)  ? 2.0f
            : (a <= 3.5f)  ? 3.0f
            : (a <= 5.0f)  ? 4.0f : 6.0f;
    qq.h[i] = (_Float16)(copysignf(v, r) * total);  // exact in f16
  }

  const int k = g * 16 + hq * 4;
  const int kb = k >> 5;
  const int quad = (k >> 3) & 3;
  const int lane16 = (m & 15) | (quad << 4);
  const int mb = m >> 4;
  asw[((kb * 8 + mb) * 64 + lane16) * 2 + (hq & 1)] = qq.v;
}

// ---------------- fp4 pair decode: 4 packed bytes (8 codes) -> 8 scaled f16 ----------------
__device__ __forceinline__ half8 decode_scale(int4 w, float sf) {
  uint32_t t0 = perm_b32((uint32_t)w.y, (uint32_t)w.x, 0x00000400u);
  uint32_t t1 = perm_b32((uint32_t)w.w, (uint32_t)w.z, 0x04000000u);
  uint32_t b  = perm_b32(t1, t0, 0x07060100u); // byte i = codes (k2i, k2i+1)
  uint32_t ev = b & 0x0F0F0F0Fu;               // even-k nibbles
  uint32_t od = (b >> 4) & 0x0F0F0F0Fu;        // odd-k nibbles
  uint32_t evm = ev & 0x07070707u;
  uint32_t odm = od & 0x07070707u;
  uint32_t evs = (ev & 0x08080808u) << 4;      // sign -> byte-high bit (f16 bit15)
  uint32_t ods = (od & 0x08080808u) << 4;
  // f16 high bytes of {0,.5,1,1.5,2,3,4,6} = {00,38,3C,3E,40,42,44,46}
  uint32_t evh = perm_b32(0x46444240u, 0x3E3C3800u, evm) | evs;
  uint32_t odh = perm_b32(0x46444240u, 0x3E3C3800u, odm) | ods;
  union { uint32_t u[4]; half8 h; } r;
  r.u[0] = perm_b32(odh, evh, 0x04000000u) & 0xFF00FF00u; // (k1,k0)
  r.u[1] = perm_b32(odh, evh, 0x05000100u) & 0xFF00FF00u; // (k3,k2)
  r.u[2] = perm_b32(odh, evh, 0x06000200u) & 0xFF00FF00u; // (k5,k4)
  r.u[3] = perm_b32(odh, evh, 0x07000300u) & 0xFF00FF00u; // (k7,k6)
  _Float16 hsf = (_Float16)sf;
  half8 sv = {hsf, hsf, hsf, hsf, hsf, hsf, hsf, hsf};
  return r.h * sv;                              // v_pk_mul_f16 x4
}

// ---------------- Kernel 2: cooperative fused dequant GEMM ----------------
// Grid 512 = 64 n-blocks x 8 k-parts (kp = bid&7 -> one k-part per XCD).
// Block: 8 waves, ALL on the same k; wave wv owns cols [nb*128+wv*16, +16), all 128 m.
// Per 32-k step: each wave reg-stages one 1KiB A-fragment into double-buffered LDS
// (issue-early/write-late), prefetches next weight int4 + scales, reads the 8 shared
// A-fragments from LDS, 8 MFMAs. Weight stream (128 MiB) is the only big HBM traffic.
// MODE 0: write f32 partials [kp][128][8192] (reduced by reduce_kernel).
// MODE 1: unsafeAtomicAdd into pre-zeroed out (small-workspace fallback).
template<int MODE>
__global__ __launch_bounds__(512, 4)
void gemm_kernel(const uint4* __restrict__ asw,
                 const int* __restrict__ wq,
                 const float* __restrict__ wsc,
                 const float* __restrict__ ws2p,
                 float* __restrict__ dst) {
  __shared__ uint4 abuf[2][8][64];    // 16 KiB double-buffered A k-slice (frag layout)
  const int lane = threadIdx.x & 63;
  const int wv = threadIdx.x >> 6;    // wave 0..7 = n-subtile
  const int quad = lane >> 4;
  const int kp = blockIdx.x & 7;      // k-part (XCD-aligned)
  const int nb = blockIdx.x >> 3;     // n-tile 0..63
  const int col = nb * 128 + wv * 16 + (lane & 15);
  const float ws2 = ws2p[0];
  const int4* wp = (const int4*)(wq + (size_t)col * 4096) + kp * 128 + quad;
  const float2* sp = (const float2*)(wsc + (size_t)col * 512 + kp * 64);
  const uint4* ap = asw + kp * 16384 + wv * 64 + lane;  // frag (kb=kp*32+t, mb=wv)

  float4v acc[8];
#pragma unroll
  for (int mb = 0; mb < 8; ++mb) acc[mb] = (float4v){0.f, 0.f, 0.f, 0.f};

  // prologue: stage step 0, load step-0 weight/scales
  {
    uint4 a0 = ap[0];
    int4 w0 = wp[0];
    float2 s0 = sp[0];
    abuf[0][wv][lane] = a0;
    __syncthreads();
    // keep in named regs via loop-carried vars below
    int4 wC = w0; float2 sC = s0;
    for (int t = 0; t < 32; ++t) {
      uint4 aN; int4 wN; float2 sN;
      const bool more = (t < 31);
      if (more) {                      // issue next-step loads EARLY (T14)
        aN = ap[(t + 1) * 512];
        wN = wp[(t + 1) * 4];
        sN = sp[t + 1];
      }
      uint4 af[8];
#pragma unroll
      for (int mb = 0; mb < 8; ++mb) af[mb] = abuf[t & 1][mb][lane];
      float sA = ((quad & 2) ? sC.y : sC.x) * ws2;
      half8 bA = decode_scale(wC, sA);
#pragma unroll
      for (int mb = 0; mb < 8; ++mb) {
        union { uint4 u; half8 h; } a;
        a.u = af[mb];
        acc[mb] = __builtin_amdgcn_mfma_f32_16x16x32_f16(a.h, bA, acc[mb], 0, 0, 0);
      }
      if (more) {                      // write-late into the other buffer, then sync
        abuf[(t + 1) & 1][wv][lane] = aN;
        __syncthreads();
        wC = wN; sC = sN;
      }
    }
  }

  // Epilogue. C/D layout: n = lane&15, m = quad*4 + reg (verified m89/m91)
  if (MODE == 0) {
    float* pp = dst + ((size_t)kp << 20) + col;
#pragma unroll
    for (int mb = 0; mb < 8; ++mb) {
      const int mrow = mb * 16 + quad * 4;
#pragma unroll
      for (int r = 0; r < 4; ++r) pp[(size_t)(mrow + r) * 8192] = acc[mb][r];
    }
  } else {
#pragma unroll
    for (int mb = 0; mb < 8; ++mb) {
      const int mrow = mb * 16 + quad * 4;
#pragma unroll
      for (int r = 0; r < 4; ++r)
        unsafeAtomicAdd(&dst[(size_t)(mrow + r) * 8192 + col], acc[mb][r]);
    }
  }
}

// ---------------- Kernel 3: k-part reduction (MODE-0 path) ----------------
__global__ __launch_bounds__(256)
void reduce_kernel(const float4* __restrict__ part, float4* __restrict__ out) {
  const int i = blockIdx.x * 256 + threadIdx.x;   // 262144 float4 = 1M floats
  float4 s = part[i];
#pragma unroll
  for (int p = 1; p < 8; ++p) {
    float4 b = part[(size_t)p * 262144 + i];
    s.x += b.x; s.y += b.y; s.z += b.z; s.w += b.w;
  }
  out[i] = s;
}

extern "C" void kernel_launch(void* const* d_in, const int* in_sizes, int n_in,
                              void* d_out, int out_size, void* d_ws, size_t ws_size,
                              hipStream_t stream) {
  (void)in_sizes; (void)n_in; (void)out_size;
  const float* hs  = (const float*)d_in[0];   // f32 [128][8192]
  const int* wq    = (const int*)d_in[1];     // int32 [8192][4096]
  const float* wsc = (const float*)d_in[2];   // f32 [8192][512]
  const float* ws2 = (const float*)d_in[3];   // f32 [1]
  const float* isc = (const float*)d_in[4];   // f32 [1]
  float* out       = (float*)d_out;           // f32 [128][8192]
  uint2* asw2      = (uint2*)d_ws;            // 2 MiB swizzled f16 A fragments (8B store view)
  const uint4* asw4 = (const uint4*)d_ws;     // same buffer, 16B fragment view

  aqdq_kernel<<<1024, 256, 0, stream>>>(hs, isc, asw2);

  const size_t need = ((size_t)2 << 20) + ((size_t)32 << 20);  // asw + partials
  if (ws_size >= need) {
    float* part = (float*)((char*)d_ws + ((size_t)2 << 20));   // f32 [8][128][8192]
    gemm_kernel<0><<<512, 512, 0, stream>>>(asw4, wq, wsc, ws2, part);
    reduce_kernel<<<1024, 256, 0, stream>>>((const float4*)part, (float4*)out);
  } else {
    hipMemsetAsync(out, 0, (size_t)128 * 8192 * 4, stream);
    gemm_kernel<1><<<512, 512, 0, stream>>>(asw4, wq, wsc, ws2, out);
  }
}